// Round 7
// baseline (1952.703 us; speedup 1.0000x reference)
//
#include <hip/hip_runtime.h>

static constexpr int TT = 512;   // sequence length
static constexpr int BB = 256;   // batch

// LDS-only barrier: no vmcnt(0) drain, so global loads stay in flight across
// it (T4/T14 pattern). lgkmcnt(0) makes prior LDS writes visible.
#define BARRIER() do { \
    asm volatile("s_waitcnt lgkmcnt(0)" ::: "memory"); \
    __builtin_amdgcn_s_barrier(); \
    asm volatile("" ::: "memory"); \
  } while (0)

__device__ __forceinline__ float sigmoid_fast(float v) {
  const float e = __builtin_amdgcn_exp2f(v * -1.44269504088896340736f);
  return __builtin_amdgcn_rcpf(1.0f + e);
}
__device__ __forceinline__ float dpp_add_xor1(float v) {
  const int p = __builtin_amdgcn_update_dpp(0, __builtin_bit_cast(int, v),
                                            0xB1, 0xF, 0xF, true);
  return v + __builtin_bit_cast(float, p);
}
__device__ __forceinline__ float dpp_add_xor2(float v) {
  const int p = __builtin_amdgcn_update_dpp(0, __builtin_bit_cast(int, v),
                                            0x4E, 0xF, 0xF, true);
  return v + __builtin_bit_cast(float, p);
}
__device__ __forceinline__ float swz_add_xor4(float v) {
  const int p = __builtin_amdgcn_ds_swizzle(__builtin_bit_cast(int, v), 0x101F);
  return v + __builtin_bit_cast(float, p);
}
// padded LDS offset: +4 words per 32 -> slice bases hit banks {0,4,8,12}
__device__ __forceinline__ constexpr int pofs(int k) { return k + ((k >> 5) << 2); }

// 128-FMA 4-gate dot over 8 float4 (SL=32), weights w[128]
#define DOT128(XV, W, AI, AF, AG, AO)                                        \
  _Pragma("unroll")                                                          \
  for (int jj = 0; jj < 8; ++jj) {                                           \
    const float4 v = (XV)[jj];                                               \
    const float* wj = &(W)[16 * jj];                                         \
    AI = fmaf(v.x, wj[0],  AI);  AF = fmaf(v.x, wj[1],  AF);                 \
    AG = fmaf(v.x, wj[2],  AG);  AO = fmaf(v.x, wj[3],  AO);                 \
    AI = fmaf(v.y, wj[4],  AI);  AF = fmaf(v.y, wj[5],  AF);                 \
    AG = fmaf(v.y, wj[6],  AG);  AO = fmaf(v.y, wj[7],  AO);                 \
    AI = fmaf(v.z, wj[8],  AI);  AF = fmaf(v.z, wj[9],  AF);                 \
    AG = fmaf(v.z, wj[10], AG);  AO = fmaf(v.z, wj[11], AO);                 \
    AI = fmaf(v.w, wj[12], AI);  AF = fmaf(v.w, wj[13], AF);                 \
    AG = fmaf(v.w, wj[14], AG);  AO = fmaf(v.w, wj[15], AO);                 \
  }

// 32-FMA 4-gate dot over 2 float4 (SL=8), weights w[32]
#define DOT32(XV, W, AI, AF, AG, AO)                                         \
  _Pragma("unroll")                                                          \
  for (int jj = 0; jj < 2; ++jj) {                                           \
    const float4 v = (XV)[jj];                                               \
    const float* wj = &(W)[16 * jj];                                         \
    AI = fmaf(v.x, wj[0],  AI);  AF = fmaf(v.x, wj[1],  AF);                 \
    AG = fmaf(v.x, wj[2],  AG);  AO = fmaf(v.x, wj[3],  AO);                 \
    AI = fmaf(v.y, wj[4],  AI);  AF = fmaf(v.y, wj[5],  AF);                 \
    AG = fmaf(v.y, wj[6],  AG);  AO = fmaf(v.y, wj[7],  AO);                 \
    AI = fmaf(v.z, wj[8],  AI);  AF = fmaf(v.z, wj[9],  AF);                 \
    AG = fmaf(v.z, wj[10], AG);  AO = fmaf(v.z, wj[11], AO);                 \
    AI = fmaf(v.w, wj[12], AI);  AF = fmaf(v.w, wj[13], AF);                 \
    AG = fmaf(v.w, wj[14], AG);  AO = fmaf(v.w, wj[15], AO);                 \
  }

// ===========================================================================
// enc1: x@Wk1 chunk-GEMM (8 steps/chunk, double-buffered LDS) + LSTM1
// (64->128) recurrence, h1 -> ws. Conflict-free layouts: padded h ping-pong,
// gate-interleaved zx1 [row][u*4+g] (write stride-1, read stride-1).
// ===========================================================================
__global__ void __launch_bounds__(512, 2)
enc1_k(const float* __restrict__ x,     // [B,T,64]
       const float* __restrict__ Wk1,   // [64,512]
       const float* __restrict__ Wr1,   // [128,512]
       const float* __restrict__ b1,    // [512]
       float* __restrict__ h1out)       // [B,T,128]
{
  const int tid = (int)threadIdx.x, b = (int)blockIdx.x;
  const int l = tid & 63, wv = tid >> 6;
  const int sl = l & 3, u = wv * 16 + (l >> 2);   // LSTM1: NSu=4
  const int ug = tid >> 2, gg = tid & 3;          // gemm col = (unit, gate)

  __shared__ __align__(16) float zx1[2][8][512];  // x@Wk1+b1, [u*4+g] order
  __shared__ __align__(16) float hpp[2][144];     // padded h ping-pong

  float w1[128];                                  // Wr1 slice (32 k x 4 gates)
  #pragma unroll
  for (int i = 0; i < 32; ++i) {
    const float* col = Wr1 + (size_t)(sl * 32 + i) * 512;
    #pragma unroll
    for (int g = 0; g < 4; ++g) w1[i * 4 + g] = col[g * 128 + u];
  }
  const float b1c = b1[gg * 128 + ug];
  float zxa[8];
  #pragma unroll
  for (int r = 0; r < 8; ++r) zxa[r] = b1c;

  if (tid < 128) hpp[0][pofs(tid)] = 0.f;         // h(-1) = 0
  const float* xb = x + (size_t)b * TT * 64;
  float cst = 0.f;
  BARRIER();

  for (int t = -8; t < TT; ++t) {
    const int j = t & 7, ch = t >> 3;
    const bool g1 = (t < TT - 8);                  // build chunk ch+1 (0..63)

    // ---- issue streamed loads FIRST (covered by LSTM compute below) ----
    float wk[8];
    float4 xa[8];
    if (g1) {
      #pragma unroll
      for (int i = 0; i < 8; ++i)
        wk[i] = Wk1[(size_t)(8 * j + i) * 512 + gg * 128 + ug];
      const float* base = xb + (size_t)(8 * (ch + 1)) * 64 + 8 * j;
      #pragma unroll
      for (int r = 0; r < 4; ++r) {                // rows 0-3 (uniform bcast)
        xa[2 * r]     = *(const float4*)(base + r * 64);
        xa[2 * r + 1] = *(const float4*)(base + r * 64 + 4);
      }
    }

    // ---- LSTM1 step t ----
    if (t >= 0) {
      const float4* xv = (const float4*)&hpp[t & 1][sl * 36];  // padded slice
      const float zq = zx1[ch & 1][j][wv * 64 + l];            // stride-1
      float ai = (sl == 0) ? zq : 0.f;
      float af = (sl == 1) ? zq : 0.f;
      float ag = (sl == 2) ? zq : 0.f;
      float ao = (sl == 3) ? zq : 0.f;
      DOT128(xv, w1, ai, af, ag, ao);
      ai = dpp_add_xor1(ai); af = dpp_add_xor1(af);
      ag = dpp_add_xor1(ag); ao = dpp_add_xor1(ao);
      ai = dpp_add_xor2(ai); af = dpp_add_xor2(af);
      ag = dpp_add_xor2(ag); ao = dpp_add_xor2(ao);
      const float gi = sigmoid_fast(ai);
      const float gf = sigmoid_fast(af);
      const float go = sigmoid_fast(ao);
      const float gg_ = fmaxf(ag, 0.f);
      cst = fmaf(gf, cst, gi * gg_);
      const float h = go * fmaxf(cst, 0.f);
      if (sl == 0) {
        hpp[(t + 1) & 1][pofs(u)] = h;
        h1out[((size_t)b * TT + t) * 128 + u] = h;
      }
    }

    // ---- gemm1: chunk ch+1, k-slice [8j,8j+8) over 8 rows ----
    if (g1) {
      #pragma unroll
      for (int r = 0; r < 4; ++r) {
        float a = zxa[r];
        a = fmaf(xa[2*r].x,   wk[0], a);  a = fmaf(xa[2*r].y,   wk[1], a);
        a = fmaf(xa[2*r].z,   wk[2], a);  a = fmaf(xa[2*r].w,   wk[3], a);
        a = fmaf(xa[2*r+1].x, wk[4], a);  a = fmaf(xa[2*r+1].y, wk[5], a);
        a = fmaf(xa[2*r+1].z, wk[6], a);  a = fmaf(xa[2*r+1].w, wk[7], a);
        zxa[r] = a;
      }
      const float* base = xb + (size_t)(8 * (ch + 1)) * 64 + 8 * j;
      #pragma unroll
      for (int r = 4; r < 8; ++r) {                // rows 4-7 (L1-hot)
        const float4 q0 = *(const float4*)(base + r * 64);
        const float4 q1 = *(const float4*)(base + r * 64 + 4);
        float a = zxa[r];
        a = fmaf(q0.x, wk[0], a);  a = fmaf(q0.y, wk[1], a);
        a = fmaf(q0.z, wk[2], a);  a = fmaf(q0.w, wk[3], a);
        a = fmaf(q1.x, wk[4], a);  a = fmaf(q1.y, wk[5], a);
        a = fmaf(q1.z, wk[6], a);  a = fmaf(q1.w, wk[7], a);
        zxa[r] = a;
      }
      if (j == 7) {
        #pragma unroll
        for (int r = 0; r < 8; ++r) {
          zx1[(ch + 1) & 1][r][tid] = zxa[r];      // stride-1 write
          zxa[r] = b1c;
        }
      }
    }
    if (t < TT - 1) BARRIER();
  }
}

// ===========================================================================
// enc2: r4-proven template instance <128,64,8>: h1 -> z (last state only)
// ===========================================================================
template<int DIN, int H, int NSu>
__global__ void __launch_bounds__(512, 2)
lstm_last(const float* __restrict__ xin, const float* __restrict__ Wk,
          const float* __restrict__ Wr, const float* __restrict__ bias,
          float* __restrict__ last_out)
{
  constexpr int KTOT = DIN + H;
  constexpr int SL   = KTOT / NSu;
  constexpr int C4H  = 4 * H;
  constexpr int XH   = DIN + H;
  constexpr int UPW  = 64 / NSu;

  const int tid = (int)threadIdx.x, b = (int)blockIdx.x;
  const int l = tid & 63, wv = tid >> 6;
  const int sl = l & (NSu - 1);
  const int u  = wv * UPW + (l / NSu);

  __shared__ __align__(16) float xh0[XH], xh1[XH];

  float w[SL * 4];
  #pragma unroll
  for (int i = 0; i < SL; ++i) {
    const int k = sl * SL + i;
    const float* col = (k < DIN) ? &Wk[(size_t)k * C4H] : &Wr[(size_t)(k - DIN) * C4H];
    #pragma unroll
    for (int g = 0; g < 4; ++g) w[i * 4 + g] = col[g * H + u];
  }
  const float bi_ = bias[u], bf_ = bias[H + u], bg_ = bias[2 * H + u], bo_ = bias[3 * H + u];

  if (tid < H) xh0[DIN + tid] = 0.f;
  if (tid < DIN / 4)
    *((float4*)xh0 + tid) = *(const float4*)&xin[(size_t)b * TT * DIN + 4 * tid];
  BARRIER();

  float cst = 0.f;
  for (int t = 0; t < TT; ++t) {
    float* xc = (t & 1) ? xh1 : xh0;
    float* xn = (t & 1) ? xh0 : xh1;

    float4 xr;
    const bool do_stage = (tid < DIN / 4) && (t + 1 < TT);
    if (do_stage) xr = *(const float4*)&xin[((size_t)b * TT + (t + 1)) * DIN + 4 * tid];

    const float4* xv = (const float4*)(xc + sl * SL);
    float ai = 0.f, af = 0.f, ag = 0.f, ao = 0.f;
    #pragma unroll
    for (int jj = 0; jj < SL / 4; ++jj) {
      const float4 v = xv[jj];
      const float* wj = &w[16 * jj];
      ai = fmaf(v.x, wj[0],  ai);  af = fmaf(v.x, wj[1],  af);
      ag = fmaf(v.x, wj[2],  ag);  ao = fmaf(v.x, wj[3],  ao);
      ai = fmaf(v.y, wj[4],  ai);  af = fmaf(v.y, wj[5],  af);
      ag = fmaf(v.y, wj[6],  ag);  ao = fmaf(v.y, wj[7],  ao);
      ai = fmaf(v.z, wj[8],  ai);  af = fmaf(v.z, wj[9],  af);
      ag = fmaf(v.z, wj[10], ag);  ao = fmaf(v.z, wj[11], ao);
      ai = fmaf(v.w, wj[12], ai);  af = fmaf(v.w, wj[13], af);
      ag = fmaf(v.w, wj[14], ao == ao ? ag : ag);  ao = fmaf(v.w, wj[15], ao);
    }
    ai = dpp_add_xor1(ai); af = dpp_add_xor1(af);
    ag = dpp_add_xor1(ag); ao = dpp_add_xor1(ao);
    ai = dpp_add_xor2(ai); af = dpp_add_xor2(af);
    ag = dpp_add_xor2(ag); ao = dpp_add_xor2(ao);
    if constexpr (NSu == 8) {
      ai = swz_add_xor4(ai); af = swz_add_xor4(af);
      ag = swz_add_xor4(ag); ao = swz_add_xor4(ao);
    }
    const float gi = sigmoid_fast(ai + bi_);
    const float gf = sigmoid_fast(af + bf_);
    const float go = sigmoid_fast(ao + bo_);
    const float gg = fmaxf(ag + bg_, 0.f);
    cst = fmaf(gf, cst, gi * gg);
    const float h = go * fmaxf(cst, 0.f);
    if (sl == 0) {
      xn[DIN + u] = h;
      if (t == TT - 1) last_out[(size_t)b * H + u] = h;
    }
    if (do_stage) *((float4*)xn + tid) = xr;
    if (t < TT - 1) BARRIER();
  }
}

// ===========================================================================
// dec_fused (r6 winner + conflict fixes): LSTM3 (const-z, z@Wd1k folded) +
// gemm3 (d1@Wd2k chunk-streamed, gate-interleaved zx3) + LSTM4 (64->128,
// padded hb2d) + TimeDistributed Dense (2-stage pipeline).
// ===========================================================================
__global__ void __launch_bounds__(512, 2)
dec_fused(const float* __restrict__ zrow,  // [B,64]
          const float* __restrict__ Wd1k,  // [64,256]
          const float* __restrict__ Wd1r,  // [64,256]
          const float* __restrict__ bd1,   // [256]
          const float* __restrict__ Wd2k,  // [64,512]
          const float* __restrict__ Wd2r,  // [128,512]
          const float* __restrict__ bd2,   // [512]
          const float* __restrict__ Wout,  // [128,64]
          const float* __restrict__ boutp, // [64]
          float* __restrict__ out)         // [B,T,64]
{
  const int tid = (int)threadIdx.x, b = (int)blockIdx.x;
  const int l = tid & 63, wv = tid >> 6;
  const int sl1 = l & 3, u1 = wv * 16 + (l >> 2);  // LSTM4: NSu=4, H=128
  const int sl2 = l & 7, u2 = wv * 8 + (l >> 3);   // LSTM3: NSu=8, H=64
  const int ug = tid >> 2, gg = tid & 3;           // gemm3 col = (unit, gate)

  __shared__ __align__(16) float zx3[2][8][512];   // d1@Wd2k+bd2, [u*4+g]
  __shared__ __align__(16) float hd1c[2][8][64];   // d1 h chunks
  __shared__ __align__(16) float hb2d[2][144];     // LSTM4 h, padded
  __shared__ __align__(16) float dp[2][512];       // dense partials
  __shared__ __align__(16) float zl[64];

  float w[32];                                     // Wd1r slice
  #pragma unroll
  for (int i = 0; i < 8; ++i) {
    const float* col = Wd1r + (size_t)(sl2 * 8 + i) * 256;
    #pragma unroll
    for (int g = 0; g < 4; ++g) w[i * 4 + g] = col[g * 64 + u2];
  }
  float w1[128];                                   // Wd2r slice
  #pragma unroll
  for (int i = 0; i < 32; ++i) {
    const float* col = Wd2r + (size_t)(sl1 * 32 + i) * 512;
    #pragma unroll
    for (int g = 0; g < 4; ++g) w1[i * 4 + g] = col[g * 128 + u1];
  }
  float wout_r[16];
  #pragma unroll
  for (int jj = 0; jj < 16; ++jj) wout_r[jj] = Wout[(size_t)(16 * wv + jj) * 64 + l];
  const float boutr = boutp[l];
  const float bd2c = bd2[gg * 128 + ug];

  if (tid < 16) ((float4*)zl)[tid] = ((const float4*)(zrow + (size_t)b * 64))[tid];
  if (tid < 64)  hd1c[1][7][tid] = 0.f;
  if (tid < 128) hb2d[1][pofs(tid)] = 0.f;
  float zxa3[8];
  #pragma unroll
  for (int r = 0; r < 8; ++r) zxa3[r] = bd2c;
  BARRIER();

  // fold z@Wd1k once (per-lane slice partials; bd1 seeded at lane sl2==0)
  float zi = (sl2 == 0) ? bd1[u2]       : 0.f;
  float zf = (sl2 == 0) ? bd1[64 + u2]  : 0.f;
  float zg = (sl2 == 0) ? bd1[128 + u2] : 0.f;
  float zo = (sl2 == 0) ? bd1[192 + u2] : 0.f;
  #pragma unroll
  for (int i = 0; i < 8; ++i) {
    const int k = sl2 * 8 + i;
    const float zv = zl[k];
    const float* col = Wd1k + (size_t)k * 256;
    zi = fmaf(zv, col[u2],       zi);
    zf = fmaf(zv, col[64 + u2],  zf);
    zg = fmaf(zv, col[128 + u2], zg);
    zo = fmaf(zv, col[192 + u2], zo);
  }

  float cst1 = 0.f, cst2 = 0.f;

  for (int t = -8; t < 530; ++t) {
    const int j = t & 7;
    const int ch = t >> 3;
    const bool rd1 = (t >= 0 && t < TT);
    const bool g3  = (t >= 8 && t < 520);          // build chunk ch-1
    const int  s   = t - 16;
    const bool rd2 = (s >= 0 && s < TT);

    float wk3r[8];
    if (g3) {
      #pragma unroll
      for (int i = 0; i < 8; ++i)
        wk3r[i] = Wd2k[(size_t)(8 * j + i) * 512 + gg * 128 + ug];
    }

    // ---- LSTM3 step t (const-z input folded in zi..zo) ----
    if (rd1) {
      const int row = t & 7, buf = ch & 1;
      const int prow = (t - 1) & 7, pbuf = ((t - 1) >> 3) & 1;
      const float4* xv = (const float4*)&hd1c[pbuf][prow][sl2 * 8];
      float ai = zi, af = zf, ag = zg, ao = zo;
      DOT32(xv, w, ai, af, ag, ao);
      ai = dpp_add_xor1(ai); af = dpp_add_xor1(af);
      ag = dpp_add_xor1(ag); ao = dpp_add_xor1(ao);
      ai = dpp_add_xor2(ai); af = dpp_add_xor2(af);
      ag = dpp_add_xor2(ag); ao = dpp_add_xor2(ao);
      ai = swz_add_xor4(ai); af = swz_add_xor4(af);
      ag = swz_add_xor4(ag); ao = swz_add_xor4(ao);
      const float gi = sigmoid_fast(ai);
      const float gf = sigmoid_fast(af);
      const float go = sigmoid_fast(ao);
      const float gg_ = fmaxf(ag, 0.f);
      cst1 = fmaf(gf, cst1, gi * gg_);
      const float h = go * fmaxf(cst1, 0.f);
      if (sl2 == 0) hd1c[buf][row][u2] = h;
    }

    // ---- LSTM4 step s (16 behind) ----
    if (rd2) {
      const int row2 = s & 7, buf2 = (s >> 3) & 1;
      const float4* xv2 = (const float4*)&hb2d[(s + 1) & 1][sl1 * 36];  // padded
      const float zq = zx3[buf2][row2][wv * 64 + l];                    // stride-1
      float ai = (sl1 == 0) ? zq : 0.f;
      float af = (sl1 == 1) ? zq : 0.f;
      float ag = (sl1 == 2) ? zq : 0.f;
      float ao = (sl1 == 3) ? zq : 0.f;
      DOT128(xv2, w1, ai, af, ag, ao);
      ai = dpp_add_xor1(ai); af = dpp_add_xor1(af);
      ag = dpp_add_xor1(ag); ao = dpp_add_xor1(ao);
      ai = dpp_add_xor2(ai); af = dpp_add_xor2(af);
      ag = dpp_add_xor2(ag); ao = dpp_add_xor2(ao);
      const float gi = sigmoid_fast(ai);
      const float gf = sigmoid_fast(af);
      const float go = sigmoid_fast(ao);
      const float gg_ = fmaxf(ag, 0.f);
      cst2 = fmaf(gf, cst2, gi * gg_);
      const float h2 = go * fmaxf(cst2, 0.f);
      if (sl1 == 0) hb2d[s & 1][pofs(u1)] = h2;
    }

    // ---- dense partial of h4(s-1); reduce of h4(s-2) ----
    if (s >= 1 && s <= TT) {
      const float* hsrc = &hb2d[(s + 1) & 1][pofs(16 * wv)];  // contiguous 16
      float a = 0.f;
      #pragma unroll
      for (int q = 0; q < 16; q += 4) {
        const float4 hv = *(const float4*)(hsrc + q);
        a = fmaf(hv.x, wout_r[q + 0], a);
        a = fmaf(hv.y, wout_r[q + 1], a);
        a = fmaf(hv.z, wout_r[q + 2], a);
        a = fmaf(hv.w, wout_r[q + 3], a);
      }
      dp[(s - 1) & 1][wv * 64 + l] = a;
    }
    if (s >= 2 && s <= TT + 1 && wv == 7) {
      const float* dq = dp[s & 1];
      float o = boutr;
      #pragma unroll
      for (int q = 0; q < 8; ++q) o += dq[q * 64 + l];
      out[((size_t)b * TT + (s - 2)) * 64 + l] = o;
    }

    // ---- gemm3: zx3 chunk ch-1 from hd1c ----
    if (g3) {
      const int cc = ch - 1;
      #pragma unroll
      for (int r = 0; r < 8; ++r) {
        const float4 ha  = *(const float4*)&hd1c[cc & 1][r][8 * j];
        const float4 hbq = *(const float4*)&hd1c[cc & 1][r][8 * j + 4];
        float a = zxa3[r];
        a = fmaf(ha.x,  wk3r[0], a);  a = fmaf(ha.y,  wk3r[1], a);
        a = fmaf(ha.z,  wk3r[2], a);  a = fmaf(ha.w,  wk3r[3], a);
        a = fmaf(hbq.x, wk3r[4], a);  a = fmaf(hbq.y, wk3r[5], a);
        a = fmaf(hbq.z, wk3r[6], a);  a = fmaf(hbq.w, wk3r[7], a);
        zxa3[r] = a;
      }
      if (j == 7) {
        #pragma unroll
        for (int r = 0; r < 8; ++r) {
          zx3[cc & 1][r][tid] = zxa3[r];           // stride-1 write
          zxa3[r] = bd2c;
        }
      }
    }

    if (t < 529) BARRIER();
  }
}

extern "C" void kernel_launch(void* const* d_in, const int* in_sizes, int n_in,
                              void* d_out, int out_size, void* d_ws, size_t ws_size,
                              hipStream_t stream) {
  const float* x    = (const float*)d_in[0];
  const float* Wk1  = (const float*)d_in[1];
  const float* Wr1  = (const float*)d_in[2];
  const float* b1   = (const float*)d_in[3];
  const float* Wk2  = (const float*)d_in[4];
  const float* Wr2  = (const float*)d_in[5];
  const float* b2   = (const float*)d_in[6];
  const float* Wd1k = (const float*)d_in[7];
  const float* Wd1r = (const float*)d_in[8];
  const float* bd1  = (const float*)d_in[9];
  const float* Wd2k = (const float*)d_in[10];
  const float* Wd2r = (const float*)d_in[11];
  const float* bd2  = (const float*)d_in[12];
  const float* Wout = (const float*)d_in[13];
  const float* bout = (const float*)d_in[14];
  float* out = (float*)d_out;

  // ws: h1 [B,T,128] (64 MB) + z [B,64]  — proven available in r4
  const size_t h1_elems = (size_t)BB * TT * 128;
  if (ws_size < (h1_elems + (size_t)BB * 64) * sizeof(float)) return;
  float* h1 = (float*)d_ws;
  float* z  = h1 + h1_elems;

  enc1_k<<<BB, 512, 0, stream>>>(x, Wk1, Wr1, b1, h1);
  lstm_last<128, 64, 8><<<BB, 512, 0, stream>>>(h1, Wk2, Wr2, b2, z);
  dec_fused<<<BB, 512, 0, stream>>>(z, Wd1k, Wd1r, bd1, Wd2k, Wd2r, bd2,
                                    Wout, bout, out);
}

// Round 8
// 1440.423 us; speedup vs baseline: 1.3556x; 1.3556x over previous
//
#include <hip/hip_runtime.h>

static constexpr int TT = 512;   // sequence length
static constexpr int BB = 256;   // batch

// LDS-only barrier: no vmcnt(0) drain, so global loads stay in flight across
// it (T4/T14 pattern). lgkmcnt(0) makes prior LDS writes visible.
#define BARRIER() do { \
    asm volatile("s_waitcnt lgkmcnt(0)" ::: "memory"); \
    __builtin_amdgcn_s_barrier(); \
    asm volatile("" ::: "memory"); \
  } while (0)

__device__ __forceinline__ float sigmoid_fast(float v) {
  const float e = __builtin_amdgcn_exp2f(v * -1.44269504088896340736f);
  return __builtin_amdgcn_rcpf(1.0f + e);
}
__device__ __forceinline__ float dpp_add_xor1(float v) {
  const int p = __builtin_amdgcn_update_dpp(0, __builtin_bit_cast(int, v),
                                            0xB1, 0xF, 0xF, true);
  return v + __builtin_bit_cast(float, p);
}
__device__ __forceinline__ float dpp_add_xor2(float v) {
  const int p = __builtin_amdgcn_update_dpp(0, __builtin_bit_cast(int, v),
                                            0x4E, 0xF, 0xF, true);
  return v + __builtin_bit_cast(float, p);
}
__device__ __forceinline__ float swz_add_xor4(float v) {
  const int p = __builtin_amdgcn_ds_swizzle(__builtin_bit_cast(int, v), 0x101F);
  return v + __builtin_bit_cast(float, p);
}
// padded LDS offset: +4 words per 32 -> 16-float slice bases spread over banks
__device__ __forceinline__ constexpr int pofs(int k) { return k + ((k >> 5) << 2); }

// r4 structure (proven 1422 us, 0 conflicts except dec1), single lever added:
// amdgpu_waves_per_eu(2,2) -> RA knows occupancy is capped at 2 waves/EU, so
// it may use the full 256 arch-VGPR tier; w[] leaves AGPRs -> no accvgpr
// copies in the hot loop. PAD fixes dec1's measured 4-way LDS conflict.
template<int DIN, int H, int NSu, bool CONST_X, bool WRITE_SEQ, bool WRITE_LAST,
         bool FUSE_DENSE, bool PAD>
__global__ void __launch_bounds__(512)
__attribute__((amdgpu_waves_per_eu(2, 2)))
lstm_unit(const float* __restrict__ xin, const float* __restrict__ Wk,
          const float* __restrict__ Wr, const float* __restrict__ bias,
          float* __restrict__ seq_out, float* __restrict__ last_out,
          const float* __restrict__ Wout, const float* __restrict__ boutp,
          float* __restrict__ dense_out)
{
  constexpr int NTH  = 512;
  static_assert(H * NSu == NTH, "block = H*NSu = 512");
  constexpr int KTOT = DIN + H;
  constexpr int SL   = KTOT / NSu;
  constexpr int C4H  = 4 * H;
  constexpr int XH   = DIN + H;
  constexpr int XHP  = PAD ? (XH + ((XH / 32) * 4)) : XH;
  constexpr int NW   = NTH / 64;
  constexpr int UPW  = 64 / NSu;
  constexpr int DK   = FUSE_DENSE ? (H / NW) : 4;
  static_assert(SL * NSu == KTOT && (SL % 4) == 0, "slice float4-able");
  static_assert(NSu == 4 || NSu == 8, "butterfly depth");
  static_assert(!PAD || (SL % 16 == 0) || (SL == 16), "pad assumes 16-float slices");

  const int tid = (int)threadIdx.x;
  const int b   = (int)blockIdx.x;
  const int l   = tid & 63;
  const int wv  = tid >> 6;
  const int sl  = l & (NSu - 1);
  const int u   = wv * UPW + (l / NSu);

  __shared__ __align__(16) float xh0[XHP], xh1[XHP];
  __shared__ __align__(16) float dp[2][FUSE_DENSE ? NW * 64 : 4];

  auto pidx = [](int k) constexpr -> int { return PAD ? pofs(k) : k; };

  float w[SL * 4];
  #pragma unroll
  for (int i = 0; i < SL; ++i) {
    const int k = sl * SL + i;
    const float* col = (k < DIN) ? &Wk[(size_t)k * C4H] : &Wr[(size_t)(k - DIN) * C4H];
    #pragma unroll
    for (int g = 0; g < 4; ++g) w[i * 4 + g] = col[g * H + u];
  }
  const float bi_ = bias[u], bf_ = bias[H + u], bg_ = bias[2 * H + u], bo_ = bias[3 * H + u];

  float wout_r[DK];
  float boutr = 0.f;
  if constexpr (FUSE_DENSE) {
    #pragma unroll
    for (int j = 0; j < DK; ++j) wout_r[j] = Wout[(size_t)(DK * wv + j) * 64 + l];
    boutr = boutp[l];
  }

  if (tid < H) xh0[pidx(DIN + tid)] = 0.f;
  if (tid < DIN / 4) {
    const float4 v = *(const float4*)&xin[(CONST_X ? (size_t)b * DIN
                                                   : (size_t)b * TT * DIN) + 4 * tid];
    *(float4*)(xh0 + pidx(4 * tid)) = v;        // 4|32 so float4 stays in-block
    if (CONST_X) *(float4*)(xh1 + pidx(4 * tid)) = v;
  }
  BARRIER();

  float cst = 0.f;
  constexpr int TEND = FUSE_DENSE ? TT + 2 : TT;

  for (int t = 0; t < TEND; ++t) {
    float* xc = (t & 1) ? xh1 : xh0;
    float* xn = (t & 1) ? xh0 : xh1;

    float4 xr;
    const bool do_stage = (!CONST_X) && (tid < DIN / 4) && (t + 1 < TT);
    if (do_stage) xr = *(const float4*)&xin[((size_t)b * TT + (t + 1)) * DIN + 4 * tid];

    if (t < TT) {
      const float4* xv = (const float4*)(xc + pidx(sl * SL));
      float ai = 0.f, af = 0.f, ag = 0.f, ao = 0.f;
      #pragma unroll
      for (int j = 0; j < SL / 4; ++j) {
        const float4 v = xv[j];
        const float* wj = &w[16 * j];
        ai = fmaf(v.x, wj[0],  ai);  af = fmaf(v.x, wj[1],  af);
        ag = fmaf(v.x, wj[2],  ag);  ao = fmaf(v.x, wj[3],  ao);
        ai = fmaf(v.y, wj[4],  ai);  af = fmaf(v.y, wj[5],  af);
        ag = fmaf(v.y, wj[6],  ag);  ao = fmaf(v.y, wj[7],  ao);
        ai = fmaf(v.z, wj[8],  ai);  af = fmaf(v.z, wj[9],  af);
        ag = fmaf(v.z, wj[10], ag);  ao = fmaf(v.z, wj[11], ao);
        ai = fmaf(v.w, wj[12], ai);  af = fmaf(v.w, wj[13], af);
        ag = fmaf(v.w, wj[14], ag);  ao = fmaf(v.w, wj[15], ao);
      }
      ai = dpp_add_xor1(ai); af = dpp_add_xor1(af);
      ag = dpp_add_xor1(ag); ao = dpp_add_xor1(ao);
      ai = dpp_add_xor2(ai); af = dpp_add_xor2(af);
      ag = dpp_add_xor2(ag); ao = dpp_add_xor2(ao);
      if constexpr (NSu == 8) {
        ai = swz_add_xor4(ai); af = swz_add_xor4(af);
        ag = swz_add_xor4(ag); ao = swz_add_xor4(ao);
      }
      const float gi = sigmoid_fast(ai + bi_);
      const float gf = sigmoid_fast(af + bf_);
      const float go = sigmoid_fast(ao + bo_);
      const float gg = fmaxf(ag + bg_, 0.f);       // activation = relu
      cst = fmaf(gf, cst, gi * gg);                // c = f*c + i*g
      const float h = go * fmaxf(cst, 0.f);        // h = o * relu(c)
      if (sl == 0) {
        xn[pidx(DIN + u)] = h;
        if constexpr (WRITE_SEQ)  seq_out[((size_t)b * TT + t) * H + u] = h;
        if constexpr (WRITE_LAST) { if (t == TT - 1) last_out[(size_t)b * H + u] = h; }
      }
    }
    if (do_stage) *(float4*)(xn + pidx(4 * tid)) = xr;

    if constexpr (FUSE_DENSE) {
      if (t >= 1 && t <= TT) {
        const float* hsrc = xc + DIN + DK * wv;    // PAD=false for dense kernel
        float a = 0.f;
        #pragma unroll
        for (int j = 0; j < DK; j += 4) {
          const float4 hv = *(const float4*)(hsrc + j);
          a = fmaf(hv.x, wout_r[j + 0], a);
          a = fmaf(hv.y, wout_r[j + 1], a);
          a = fmaf(hv.z, wout_r[j + 2], a);
          a = fmaf(hv.w, wout_r[j + 3], a);
        }
        dp[(t - 1) & 1][wv * 64 + l] = a;
      }
      if (t >= 2 && wv == NW - 1) {
        const float* dq = dp[t & 1];
        float o = boutr;
        #pragma unroll
        for (int j = 0; j < NW; ++j) o += dq[j * 64 + l];
        dense_out[((size_t)b * TT + (t - 2)) * 64 + l] = o;
      }
    }
    if (t < TEND - 1) BARRIER();
  }
}

extern "C" void kernel_launch(void* const* d_in, const int* in_sizes, int n_in,
                              void* d_out, int out_size, void* d_ws, size_t ws_size,
                              hipStream_t stream) {
  const float* x    = (const float*)d_in[0];
  const float* Wk1  = (const float*)d_in[1];
  const float* Wr1  = (const float*)d_in[2];
  const float* b1   = (const float*)d_in[3];
  const float* Wk2  = (const float*)d_in[4];
  const float* Wr2  = (const float*)d_in[5];
  const float* b2   = (const float*)d_in[6];
  const float* Wd1k = (const float*)d_in[7];
  const float* Wd1r = (const float*)d_in[8];
  const float* bd1  = (const float*)d_in[9];
  const float* Wd2k = (const float*)d_in[10];
  const float* Wd2r = (const float*)d_in[11];
  const float* bd2  = (const float*)d_in[12];
  const float* Wout = (const float*)d_in[13];
  const float* bout = (const float*)d_in[14];
  float* out = (float*)d_out;

  // ws: h1 [B,T,128] (64 MB; d1 [B,T,64] overlays it after enc2), z [B,64]
  const size_t h1_elems = (size_t)BB * TT * 128;
  if (ws_size < (h1_elems + (size_t)BB * 64) * sizeof(float)) return;
  float* h1 = (float*)d_ws;
  float* z  = h1 + h1_elems;
  float* d1 = h1;  // h1 dead after enc2

  // encoder 1: 64 -> 128, seq out           (NSu=4, SL=48, w[192])
  lstm_unit<64, 128, 4, false, true,  false, false, false><<<BB, 512, 0, stream>>>(
      x,  Wk1,  Wr1,  b1,  h1,      nullptr, nullptr, nullptr, nullptr);
  // encoder 2: 128 -> 64, last state only   (NSu=8, SL=24, w[96])
  lstm_unit<128, 64, 8, false, false, true,  false, false><<<BB, 512, 0, stream>>>(
      h1, Wk2,  Wr2,  b2,  nullptr, z,       nullptr, nullptr, nullptr);
  // decoder 1: const z (RepeatVector) -> 64 (NSu=8, SL=16, w[64], PAD fixes
  // the measured 1.7e7 4-way LDS conflict on sl*16 reads)
  lstm_unit<64,  64, 8, true,  true,  false, false, true ><<<BB, 512, 0, stream>>>(
      z,  Wd1k, Wd1r, bd1, d1,      nullptr, nullptr, nullptr, nullptr);
  // decoder 2: 64 -> 128 + fused Dense 128->64 (NSu=4, SL=48, w[192]+wout[16])
  lstm_unit<64, 128, 4, false, false, false, true,  false><<<BB, 512, 0, stream>>>(
      d1, Wd2k, Wd2r, bd2, nullptr, nullptr, Wout,   bout,    out);
}